// Round 11
// baseline (186.164 us; speedup 1.0000x reference)
//
#include <hip/hip_runtime.h>
#include <hip/hip_fp16.h>
#include <math.h>

#define N_NODES 262144
#define N_EDGES 4194304
#define N_GRAPHS 1024
#define NBK 512                  // dst buckets (512 nodes each)
#define CAP 8960                 // per-bucket capacity (mean 8192 + 8.5 sigma)
#define ABLK 512                 // fusedAB blocks
#define AEPB (N_EDGES / ABLK)    // 8192 edges per block; run = 16 edges = 64B

typedef _Float16 half2v __attribute__((ext_vector_type(2)));
__device__ inline half2v u2h(unsigned u) { union { unsigned u; half2v h; } c; c.u = u; return c.h; }
__device__ inline unsigned packh2(float a, float b) {
    union { __half2 h; unsigned u; } c; c.h = __floats2half2_rn(a, b); return c.u;
}

// ---------------------------------------------------------------------------
// fusedAB: pack px16 + zero pooled + per-block bucket hist (int4 reads) +
// global range reservation + line-dense binned scatter of (src | dstlow<<18).
// ---------------------------------------------------------------------------
__global__ __launch_bounds__(256) void fusedAB(
    const int* __restrict__ ei, const float* __restrict__ x,
    const float* __restrict__ pos, int* __restrict__ gcur,
    int* __restrict__ binned, uint4* __restrict__ px16,
    float* __restrict__ pooled)
{
    __shared__ int lh[NBK];
    int t = threadIdx.x, b = blockIdx.x;

    // pack 2 nodes per thread (fp16 x4 + pos3 -> one 16B record, 4MB total)
    #pragma unroll
    for (int k = 0; k < 2; ++k) {
        int n = b * 512 + k * 256 + t;
        float4 v = ((const float4*)x)[n];
        float p0 = pos[3 * n], p1 = pos[3 * n + 1], p2 = pos[3 * n + 2];
        uint4 r;
        r.x = packh2(v.x, v.y);
        r.y = packh2(v.z, v.w);
        r.z = packh2(p0, p1);
        r.w = packh2(p2, 0.0f);
        px16[n] = r;
    }
    int pid = b * 256 + t;
    if (pid < 1025 * 32) pooled[pid] = 0.0f;

    #pragma unroll
    for (int k = 0; k < 2; ++k) lh[t + 256 * k] = 0;
    __syncthreads();

    const int4* dsts = (const int4*)(ei + N_EDGES + b * AEPB);
    #pragma unroll
    for (int i = 0; i < AEPB / 1024; ++i) {
        int4 d4 = dsts[i * 256 + t];
        atomicAdd(&lh[d4.x >> 9], 1);
        atomicAdd(&lh[d4.y >> 9], 1);
        atomicAdd(&lh[d4.z >> 9], 1);
        atomicAdd(&lh[d4.w >> 9], 1);
    }
    __syncthreads();
    #pragma unroll
    for (int k = 0; k < 2; ++k) {
        int kb = t + 256 * k;
        lh[kb] = atomicAdd(&gcur[kb * 16], lh[kb]);   // reserve contiguous range
    }
    __syncthreads();
    int base = b * AEPB;
    for (int i = 0; i < AEPB / 256; ++i) {
        int e = base + i * 256 + t;
        int s = ei[e];
        int d = ei[N_EDGES + e];
        int slot = atomicAdd(&lh[d >> 9], 1);
        if (slot < CAP)
            binned[(size_t)(d >> 9) * CAP + slot] = s | ((d & 511) << 18);
    }
}

// ---------------------------------------------------------------------------
// passC: per-bucket node sort, in place (binned -> node-grouped src ids),
// PLUS per-bucket counting sort of nodes by degree -> perm. Deg-sorted
// processing order kills the gather's max-over-4-groups divergence.
// ---------------------------------------------------------------------------
__global__ __launch_bounds__(512) void passC_sort(
    const int* __restrict__ gcur,
    int* __restrict__ binned,
    int* __restrict__ startg, int* __restrict__ degg,
    int* __restrict__ perm)
{
    __shared__ int lbuf[CAP];
    __shared__ int ldeg[512], sc2[512], lcur[512];
    __shared__ int dh[64];
    int t = threadIdx.x, k = blockIdx.x;
    int ebase = k * CAP;
    int cnt = gcur[k * 16];
    if (cnt > CAP) cnt = CAP;

    ldeg[t] = 0;
    if (t < 64) dh[t] = 0;
    __syncthreads();
    for (int i = t; i < cnt; i += 512) {
        int pk = binned[ebase + i];
        lbuf[i] = pk;
        atomicAdd(&ldeg[pk >> 18], 1);
    }
    __syncthreads();
    int dgv = ldeg[t];
    sc2[t] = dgv;
    int bin = dgv < 63 ? dgv : 63;
    atomicAdd(&dh[bin], 1);
    __syncthreads();
    for (int o = 1; o < 512; o <<= 1) {
        int u = (t >= o) ? sc2[t - o] : 0;
        __syncthreads();
        sc2[t] += u;
        __syncthreads();
    }
    int excl = sc2[t] - dgv;
    int n = k * 512 + t;
    startg[n] = ebase + excl;
    degg[n] = dgv;
    lcur[t] = excl;
    if (t == 0) {   // serial 64-bin exclusive scan (once per block)
        int acc = 0;
        #pragma unroll
        for (int i = 0; i < 64; ++i) { int c = dh[i]; dh[i] = acc; acc += c; }
    }
    __syncthreads();
    int slot = atomicAdd(&dh[bin], 1);
    perm[(k << 9) + slot] = n;
    for (int i = t; i < cnt; i += 512) {
        int pk = lbuf[i];
        int sl = atomicAdd(&lcur[pk >> 18], 1);
        binned[ebase + sl] = pk & 0x3FFFF;
    }
}

// ---------------------------------------------------------------------------
// Gather + edge MLP (R7-verified inner loop). Nodes processed in deg-sorted
// perm order -> the 4 groups of a wave have near-equal deg. W2 applied once
// per node via LDS transpose. Pooling generalized to 8 graph rows per block.
// ---------------------------------------------------------------------------
__global__ __launch_bounds__(256) void node_gather_fused(
    const uint4* __restrict__ px16,
    const int* __restrict__ srcs, const int* __restrict__ startg,
    const int* __restrict__ degg, const int* __restrict__ perm,
    const float* __restrict__ W1, const float* __restrict__ b1,
    const float* __restrict__ W2, const float* __restrict__ b2,
    const float* __restrict__ Wp, const float* __restrict__ bp,
    const int* __restrict__ batch,
    float* __restrict__ out_s, float* __restrict__ pooled)
{
    __shared__ uint4 sepk[16][17];   // staged edges: {x01,x23,dist,pad}
    __shared__ float smh[16][20];    // sumH transpose (padded rows)
    __shared__ float lpool[8][33];
    __shared__ int sg0;

    int t = threadIdx.x;
    int g = t & 15;
    int grp = t >> 4;
    int n = perm[blockIdx.x * 16 + grp];

    // per-lane weights (registers)
    float w1c0 = W1[0 * 16 + g], w1c1 = W1[1 * 16 + g];
    float w1c2 = W1[2 * 16 + g], w1c3 = W1[3 * 16 + g];
    half2v wh45, wh67;
    wh45[0] = (_Float16)W1[4 * 16 + g];
    wh45[1] = (_Float16)W1[5 * 16 + g];
    wh67[0] = (_Float16)W1[6 * 16 + g];
    wh67[1] = (_Float16)W1[7 * 16 + g];
    float w1c8 = W1[8 * 16 + g];
    float b1g = b1[g], b2g = b2[g];
    float w2col[16];
    #pragma unroll
    for (int i = 0; i < 16; ++i) w2col[i] = W2[i * 16 + g];  // column g
    float wp0 = Wp[2 * g], wp1 = Wp[2 * g + 1];

    int base = startg[n];
    int dg = degg[n];

    // self record
    uint4 rn = px16[n];
    float2 f01 = __half22float2(*(__half2*)&rn.x);
    float2 f23 = __half22float2(*(__half2*)&rn.y);
    float2 f45 = __half22float2(*(__half2*)&rn.z);
    float2 f67 = __half22float2(*(__half2*)&rn.w);
    float pnx = f45.x, pny = f45.y, pnz = f67.x;
    float pre = b1g + f01.x * w1c0 + f01.y * w1c1 + f23.x * w1c2 + f23.y * w1c3;

    float sumH = 0.0f;

    // pipeline prologue
    int sC = 0;
    if (g < dg) sC = srcs[base + g];
    uint4 rC = px16[sC];
    int sN = sC;
    if (16 + g < dg) sN = srcs[base + 16 + g];

    for (int k0 = 0; k0 < dg; k0 += 16) {
        int rem = dg - k0;
        int cnt = rem < 16 ? rem : 16;
        if (g < cnt) {
            float2 e45 = __half22float2(*(__half2*)&rC.z);
            float2 e67 = __half22float2(*(__half2*)&rC.w);
            float dx = e45.x - pnx, dy = e45.y - pny, dz = e67.x - pnz;
            float dist = sqrtf(dx * dx + dy * dy + dz * dz);
            sepk[grp][g] = make_uint4(rC.x, rC.y, __float_as_uint(dist), 0u);
        }
        // issue next chunk's loads
        uint4 rNext = px16[sN];
        int sNN = sN;
        if (k0 + 32 + g < dg) sNN = srcs[base + k0 + 32 + g];
        // compute current chunk from LDS (2x unrolled to batch waits)
        int j = 0;
        for (; j + 1 < cnt; j += 2) {
            uint4 A = sepk[grp][j];
            uint4 B = sepk[grp][j + 1];
            float a = fmaf(__uint_as_float(A.z), w1c8, pre);
            a = __builtin_amdgcn_fdot2(u2h(A.x), wh45, a, false);
            a = __builtin_amdgcn_fdot2(u2h(A.y), wh67, a, false);
            sumH += a * __builtin_amdgcn_rcpf(1.0f + __expf(-a));
            float b = fmaf(__uint_as_float(B.z), w1c8, pre);
            b = __builtin_amdgcn_fdot2(u2h(B.x), wh45, b, false);
            b = __builtin_amdgcn_fdot2(u2h(B.y), wh67, b, false);
            sumH += b * __builtin_amdgcn_rcpf(1.0f + __expf(-b));
        }
        if (j < cnt) {
            uint4 A = sepk[grp][j];
            float a = fmaf(__uint_as_float(A.z), w1c8, pre);
            a = __builtin_amdgcn_fdot2(u2h(A.x), wh45, a, false);
            a = __builtin_amdgcn_fdot2(u2h(A.y), wh67, a, false);
            sumH += a * __builtin_amdgcn_rcpf(1.0f + __expf(-a));
        }
        rC = rNext;
        sN = sNN;
    }

    // LDS-transpose epilogue: lane g applies W2 column g.
    smh[grp][g] = sumH;
    float4 s0v = *(const float4*)&smh[grp][0];
    float4 s1v = *(const float4*)&smh[grp][4];
    float4 s2v = *(const float4*)&smh[grp][8];
    float4 s3v = *(const float4*)&smh[grp][12];
    float red = s0v.x * w2col[0] + s0v.y * w2col[1] + s0v.z * w2col[2] + s0v.w * w2col[3]
              + s1v.x * w2col[4] + s1v.y * w2col[5] + s1v.z * w2col[6] + s1v.w * w2col[7]
              + s2v.x * w2col[8] + s2v.y * w2col[9] + s2v.z * w2col[10] + s2v.w * w2col[11]
              + s3v.x * w2col[12] + s3v.y * w2col[13] + s3v.z * w2col[14] + s3v.w * w2col[15];

    float fdg = (float)dg;
    float inv = 1.0f / fmaxf(fdg, 1.0f);
    float h = fmaxf((red + fdg * b2g) * inv, 0.0f);

    // logits via 16-lane allreduce
    float c0 = h * wp0, c1 = h * wp1;
    #pragma unroll
    for (int mset = 8; mset > 0; mset >>= 1) {
        c0 += __shfl_xor(c0, mset);
        c1 += __shfl_xor(c1, mset);
    }
    float l0 = c0 + bp[0], l1 = c1 + bp[1];
    float mx = fmaxf(l0, l1);
    float e0s = __expf(l0 - mx), e1s = __expf(l1 - mx);
    float isum = 1.0f / (e0s + e1s);
    float s0 = e0s * isum, s1 = e1s * isum;

    if (g == 0) ((float2*)out_s)[n] = make_float2(s0, s1);

    // pooling: block nodes span <=8 graphs of the bucket (bucket = blk>>5)
    if (t == 0) sg0 = batch[(blockIdx.x >> 5) << 9];
    lpool[t >> 5][t & 31] = 0.0f;
    __syncthreads();

    int gid = batch[n];
    int idx = gid - sg0;
    float p0 = s0 * h, p1 = s1 * h;
    if (idx < 8) {
        atomicAdd(&lpool[idx][g], p0);
        atomicAdd(&lpool[idx][16 + g], p1);
    } else {  // pathological tiny-graph fallback
        atomicAdd(&pooled[gid * 32 + g], p0);
        atomicAdd(&pooled[gid * 32 + 16 + g], p1);
    }
    __syncthreads();
    float v = lpool[t >> 5][t & 31];
    if (v != 0.0f) atomicAdd(&pooled[(sg0 + (t >> 5)) * 32 + (t & 31)], v);
}

// ---------------------------------------------------------------------------
// z = pooled.reshape(G,32) @ Wz + bz
// ---------------------------------------------------------------------------
__global__ __launch_bounds__(256) void z_kernel(const float* __restrict__ pooled,
                                                const float* __restrict__ Wz,
                                                const float* __restrict__ bz,
                                                float* __restrict__ out_z) {
    int idx = blockIdx.x * 256 + threadIdx.x;
    if (idx >= N_GRAPHS * 8) return;
    int gph = idx >> 3, o = idx & 7;
    float a = bz[o];
    const float* pp = pooled + (size_t)gph * 32;
    #pragma unroll
    for (int j = 0; j < 32; ++j) a = fmaf(pp[j], Wz[j * 8 + o], a);
    out_z[idx] = a;
}

extern "C" void kernel_launch(void* const* d_in, const int* in_sizes, int n_in,
                              void* d_out, int out_size, void* d_ws, size_t ws_size,
                              hipStream_t stream) {
    const float* x    = (const float*)d_in[0];
    const float* pos  = (const float*)d_in[1];
    const float* W1   = (const float*)d_in[2];
    const float* b1   = (const float*)d_in[3];
    const float* W2   = (const float*)d_in[4];
    const float* b2   = (const float*)d_in[5];
    const float* Wp   = (const float*)d_in[6];
    const float* bp   = (const float*)d_in[7];
    const float* Wz   = (const float*)d_in[8];
    const float* bz   = (const float*)d_in[9];
    const int*   ei   = (const int*)d_in[10];
    const int*   batch= (const int*)d_in[11];
    float* out = (float*)d_out;
    float* out_z = out;                   // [1024*8]
    float* out_s = out + N_GRAPHS * 8;    // [262144*2]

    // ws (ints): gcur[NBK*16] | binned[NBK*CAP] (=srcs after passC) |
    //            startg[N] | degg[N] | perm[N] | pooled[1025*32] | px16[N uint4]
    int* gcur     = (int*)d_ws;
    int* binned   = gcur + NBK * 16;
    int* startg   = binned + (size_t)NBK * CAP;
    int* degg     = startg + N_NODES;
    int* perm     = degg + N_NODES;
    float* pooled = (float*)(perm + N_NODES);
    uint4* px16   = (uint4*)(pooled + 1025 * 32);   // offset is 16B-aligned

    hipMemsetAsync(gcur, 0, NBK * 16 * sizeof(int), stream);
    fusedAB<<<ABLK, 256, 0, stream>>>(ei, x, pos, gcur, binned, px16, pooled);
    passC_sort<<<NBK, 512, 0, stream>>>(gcur, binned, startg, degg, perm);
    node_gather_fused<<<N_NODES / 16, 256, 0, stream>>>(
        px16, binned, startg, degg, perm, W1, b1, W2, b2, Wp, bp, batch, out_s, pooled);
    z_kernel<<<32, 256, 0, stream>>>(pooled, Wz, bz, out_z);
}

// Round 12
// 185.651 us; speedup vs baseline: 1.0028x; 1.0028x over previous
//
#include <hip/hip_runtime.h>
#include <hip/hip_fp16.h>
#include <math.h>

#define N_NODES 262144
#define N_EDGES 4194304
#define N_GRAPHS 1024
#define NBK 512                  // dst buckets (512 nodes each)
#define CAP 8960                 // per-bucket capacity (mean 8192 + 8.5 sigma)
#define ABLK 512                 // fusedAB blocks
#define AEPB (N_EDGES / ABLK)    // 8192 edges per block; run = 16 edges = 64B

typedef _Float16 half2v __attribute__((ext_vector_type(2)));
__device__ inline half2v u2h(unsigned u) { union { unsigned u; half2v h; } c; c.u = u; return c.h; }
__device__ inline unsigned packh2(float a, float b) {
    union { __half2 h; unsigned u; } c; c.h = __floats2half2_rn(a, b); return c.u;
}

// ---------------------------------------------------------------------------
// fusedAB: pack px16 + zero pooled + per-block bucket hist (int4 reads) +
// global range reservation + line-dense binned scatter of (src | dstlow<<18).
// ---------------------------------------------------------------------------
__global__ __launch_bounds__(256) void fusedAB(
    const int* __restrict__ ei, const float* __restrict__ x,
    const float* __restrict__ pos, int* __restrict__ gcur,
    int* __restrict__ binned, uint4* __restrict__ px16,
    float* __restrict__ pooled)
{
    __shared__ int lh[NBK];
    int t = threadIdx.x, b = blockIdx.x;

    // pack 2 nodes per thread (fp16 x4 + pos3 -> one 16B record, 4MB total)
    #pragma unroll
    for (int k = 0; k < 2; ++k) {
        int n = b * 512 + k * 256 + t;
        float4 v = ((const float4*)x)[n];
        float p0 = pos[3 * n], p1 = pos[3 * n + 1], p2 = pos[3 * n + 2];
        uint4 r;
        r.x = packh2(v.x, v.y);
        r.y = packh2(v.z, v.w);
        r.z = packh2(p0, p1);
        r.w = packh2(p2, 0.0f);
        px16[n] = r;
    }
    int pid = b * 256 + t;
    if (pid < 1025 * 32) pooled[pid] = 0.0f;

    #pragma unroll
    for (int k = 0; k < 2; ++k) lh[t + 256 * k] = 0;
    __syncthreads();

    const int4* dsts = (const int4*)(ei + N_EDGES + b * AEPB);
    #pragma unroll
    for (int i = 0; i < AEPB / 1024; ++i) {
        int4 d4 = dsts[i * 256 + t];
        atomicAdd(&lh[d4.x >> 9], 1);
        atomicAdd(&lh[d4.y >> 9], 1);
        atomicAdd(&lh[d4.z >> 9], 1);
        atomicAdd(&lh[d4.w >> 9], 1);
    }
    __syncthreads();
    #pragma unroll
    for (int k = 0; k < 2; ++k) {
        int kb = t + 256 * k;
        lh[kb] = atomicAdd(&gcur[kb * 16], lh[kb]);   // reserve contiguous range
    }
    __syncthreads();
    int base = b * AEPB;
    for (int i = 0; i < AEPB / 256; ++i) {
        int e = base + i * 256 + t;
        int s = ei[e];
        int d = ei[N_EDGES + e];
        int slot = atomicAdd(&lh[d >> 9], 1);
        if (slot < CAP)
            binned[(size_t)(d >> 9) * CAP + slot] = s | ((d & 511) << 18);
    }
}

// ---------------------------------------------------------------------------
// passC: per-bucket counting sort of nodes by degree -> perm, then in-place
// rewrite of binned into PERM-ORDERED node-grouped src lists. CSR layout thus
// matches the gather's processing order: sequential srcs reads AND equal-deg
// wave groups.
// ---------------------------------------------------------------------------
__global__ __launch_bounds__(512) void passC_sort(
    const int* __restrict__ gcur,
    int* __restrict__ binned,
    int* __restrict__ startg, int* __restrict__ degg,
    int* __restrict__ perm)
{
    __shared__ int lbuf[CAP];
    __shared__ int ldeg[512], rdeg[512], lcur[512];
    __shared__ int dh[64];
    int t = threadIdx.x, k = blockIdx.x;
    int ebase = k * CAP;
    int cnt = gcur[k * 16];
    if (cnt > CAP) cnt = CAP;

    ldeg[t] = 0;
    if (t < 64) dh[t] = 0;
    __syncthreads();
    for (int i = t; i < cnt; i += 512) {
        int pk = binned[ebase + i];
        lbuf[i] = pk;
        atomicAdd(&ldeg[pk >> 18], 1);
    }
    __syncthreads();
    int dgv = ldeg[t];
    int bin = dgv < 63 ? dgv : 63;
    atomicAdd(&dh[bin], 1);
    __syncthreads();
    if (t == 0) {   // serial 64-bin exclusive scan (once per block)
        int acc = 0;
        #pragma unroll
        for (int i = 0; i < 64; ++i) { int c = dh[i]; dh[i] = acc; acc += c; }
    }
    __syncthreads();
    int r = atomicAdd(&dh[bin], 1);      // deg-sorted rank of this node
    int n = k * 512 + t;
    perm[(k << 9) + r] = n;
    rdeg[r] = dgv;
    __syncthreads();
    // Hillis-Steele inclusive scan over rank-ordered degrees (reuse ldeg)
    ldeg[t] = rdeg[t];
    __syncthreads();
    for (int o = 1; o < 512; o <<= 1) {
        int u = (t >= o) ? ldeg[t - o] : 0;
        __syncthreads();
        ldeg[t] += u;
        __syncthreads();
    }
    int excl = ldeg[r] - rdeg[r];        // perm-order offset for this node
    startg[n] = ebase + excl;
    degg[n] = dgv;
    lcur[t] = excl;
    __syncthreads();
    for (int i = t; i < cnt; i += 512) {
        int pk = lbuf[i];
        int sl = atomicAdd(&lcur[pk >> 18], 1);
        binned[ebase + sl] = pk & 0x3FFFF;
    }
}

// ---------------------------------------------------------------------------
// Gather + edge MLP (R7-verified inner loop). Nodes processed in deg-sorted
// perm order; CSR is perm-ordered so srcs reads are sequential. W2 applied
// once per node via LDS transpose. Pooling over <=8 graph rows per block.
// ---------------------------------------------------------------------------
__global__ __launch_bounds__(256) void node_gather_fused(
    const uint4* __restrict__ px16,
    const int* __restrict__ srcs, const int* __restrict__ startg,
    const int* __restrict__ degg, const int* __restrict__ perm,
    const float* __restrict__ W1, const float* __restrict__ b1,
    const float* __restrict__ W2, const float* __restrict__ b2,
    const float* __restrict__ Wp, const float* __restrict__ bp,
    const int* __restrict__ batch,
    float* __restrict__ out_s, float* __restrict__ pooled)
{
    __shared__ uint4 sepk[16][17];   // staged edges: {x01,x23,dist,pad}
    __shared__ float smh[16][20];    // sumH transpose (padded rows)
    __shared__ float lpool[8][33];
    __shared__ int sg0;

    int t = threadIdx.x;
    int g = t & 15;
    int grp = t >> 4;
    int n = perm[blockIdx.x * 16 + grp];

    // per-lane weights (registers)
    float w1c0 = W1[0 * 16 + g], w1c1 = W1[1 * 16 + g];
    float w1c2 = W1[2 * 16 + g], w1c3 = W1[3 * 16 + g];
    half2v wh45, wh67;
    wh45[0] = (_Float16)W1[4 * 16 + g];
    wh45[1] = (_Float16)W1[5 * 16 + g];
    wh67[0] = (_Float16)W1[6 * 16 + g];
    wh67[1] = (_Float16)W1[7 * 16 + g];
    float w1c8 = W1[8 * 16 + g];
    float b1g = b1[g], b2g = b2[g];
    float w2col[16];
    #pragma unroll
    for (int i = 0; i < 16; ++i) w2col[i] = W2[i * 16 + g];  // column g
    float wp0 = Wp[2 * g], wp1 = Wp[2 * g + 1];

    int base = startg[n];
    int dg = degg[n];

    // self record
    uint4 rn = px16[n];
    float2 f01 = __half22float2(*(__half2*)&rn.x);
    float2 f23 = __half22float2(*(__half2*)&rn.y);
    float2 f45 = __half22float2(*(__half2*)&rn.z);
    float2 f67 = __half22float2(*(__half2*)&rn.w);
    float pnx = f45.x, pny = f45.y, pnz = f67.x;
    float pre = b1g + f01.x * w1c0 + f01.y * w1c1 + f23.x * w1c2 + f23.y * w1c3;

    float sumH = 0.0f;

    // pipeline prologue
    int sC = 0;
    if (g < dg) sC = srcs[base + g];
    uint4 rC = px16[sC];
    int sN = sC;
    if (16 + g < dg) sN = srcs[base + 16 + g];

    for (int k0 = 0; k0 < dg; k0 += 16) {
        int rem = dg - k0;
        int cnt = rem < 16 ? rem : 16;
        if (g < cnt) {
            float2 e45 = __half22float2(*(__half2*)&rC.z);
            float2 e67 = __half22float2(*(__half2*)&rC.w);
            float dx = e45.x - pnx, dy = e45.y - pny, dz = e67.x - pnz;
            float dist = sqrtf(dx * dx + dy * dy + dz * dz);
            sepk[grp][g] = make_uint4(rC.x, rC.y, __float_as_uint(dist), 0u);
        }
        // issue next chunk's loads
        uint4 rNext = px16[sN];
        int sNN = sN;
        if (k0 + 32 + g < dg) sNN = srcs[base + k0 + 32 + g];
        // compute current chunk from LDS (2x unrolled to batch waits)
        int j = 0;
        for (; j + 1 < cnt; j += 2) {
            uint4 A = sepk[grp][j];
            uint4 B = sepk[grp][j + 1];
            float a = fmaf(__uint_as_float(A.z), w1c8, pre);
            a = __builtin_amdgcn_fdot2(u2h(A.x), wh45, a, false);
            a = __builtin_amdgcn_fdot2(u2h(A.y), wh67, a, false);
            sumH += a * __builtin_amdgcn_rcpf(1.0f + __expf(-a));
            float b = fmaf(__uint_as_float(B.z), w1c8, pre);
            b = __builtin_amdgcn_fdot2(u2h(B.x), wh45, b, false);
            b = __builtin_amdgcn_fdot2(u2h(B.y), wh67, b, false);
            sumH += b * __builtin_amdgcn_rcpf(1.0f + __expf(-b));
        }
        if (j < cnt) {
            uint4 A = sepk[grp][j];
            float a = fmaf(__uint_as_float(A.z), w1c8, pre);
            a = __builtin_amdgcn_fdot2(u2h(A.x), wh45, a, false);
            a = __builtin_amdgcn_fdot2(u2h(A.y), wh67, a, false);
            sumH += a * __builtin_amdgcn_rcpf(1.0f + __expf(-a));
        }
        rC = rNext;
        sN = sNN;
    }

    // LDS-transpose epilogue: lane g applies W2 column g.
    smh[grp][g] = sumH;
    float4 s0v = *(const float4*)&smh[grp][0];
    float4 s1v = *(const float4*)&smh[grp][4];
    float4 s2v = *(const float4*)&smh[grp][8];
    float4 s3v = *(const float4*)&smh[grp][12];
    float red = s0v.x * w2col[0] + s0v.y * w2col[1] + s0v.z * w2col[2] + s0v.w * w2col[3]
              + s1v.x * w2col[4] + s1v.y * w2col[5] + s1v.z * w2col[6] + s1v.w * w2col[7]
              + s2v.x * w2col[8] + s2v.y * w2col[9] + s2v.z * w2col[10] + s2v.w * w2col[11]
              + s3v.x * w2col[12] + s3v.y * w2col[13] + s3v.z * w2col[14] + s3v.w * w2col[15];

    float fdg = (float)dg;
    float inv = 1.0f / fmaxf(fdg, 1.0f);
    float h = fmaxf((red + fdg * b2g) * inv, 0.0f);

    // logits via 16-lane allreduce
    float c0 = h * wp0, c1 = h * wp1;
    #pragma unroll
    for (int mset = 8; mset > 0; mset >>= 1) {
        c0 += __shfl_xor(c0, mset);
        c1 += __shfl_xor(c1, mset);
    }
    float l0 = c0 + bp[0], l1 = c1 + bp[1];
    float mx = fmaxf(l0, l1);
    float e0s = __expf(l0 - mx), e1s = __expf(l1 - mx);
    float isum = 1.0f / (e0s + e1s);
    float s0 = e0s * isum, s1 = e1s * isum;

    if (g == 0) ((float2*)out_s)[n] = make_float2(s0, s1);

    // pooling: block nodes span <=8 graphs of the bucket (bucket = blk>>5)
    if (t == 0) sg0 = batch[(blockIdx.x >> 5) << 9];
    lpool[t >> 5][t & 31] = 0.0f;
    __syncthreads();

    int gid = batch[n];
    int idx = gid - sg0;
    float p0 = s0 * h, p1 = s1 * h;
    if (idx < 8) {
        atomicAdd(&lpool[idx][g], p0);
        atomicAdd(&lpool[idx][16 + g], p1);
    } else {  // pathological tiny-graph fallback
        atomicAdd(&pooled[gid * 32 + g], p0);
        atomicAdd(&pooled[gid * 32 + 16 + g], p1);
    }
    __syncthreads();
    float v = lpool[t >> 5][t & 31];
    if (v != 0.0f) atomicAdd(&pooled[(sg0 + (t >> 5)) * 32 + (t & 31)], v);
}

// ---------------------------------------------------------------------------
// z = pooled.reshape(G,32) @ Wz + bz
// ---------------------------------------------------------------------------
__global__ __launch_bounds__(256) void z_kernel(const float* __restrict__ pooled,
                                                const float* __restrict__ Wz,
                                                const float* __restrict__ bz,
                                                float* __restrict__ out_z) {
    int idx = blockIdx.x * 256 + threadIdx.x;
    if (idx >= N_GRAPHS * 8) return;
    int gph = idx >> 3, o = idx & 7;
    float a = bz[o];
    const float* pp = pooled + (size_t)gph * 32;
    #pragma unroll
    for (int j = 0; j < 32; ++j) a = fmaf(pp[j], Wz[j * 8 + o], a);
    out_z[idx] = a;
}

extern "C" void kernel_launch(void* const* d_in, const int* in_sizes, int n_in,
                              void* d_out, int out_size, void* d_ws, size_t ws_size,
                              hipStream_t stream) {
    const float* x    = (const float*)d_in[0];
    const float* pos  = (const float*)d_in[1];
    const float* W1   = (const float*)d_in[2];
    const float* b1   = (const float*)d_in[3];
    const float* W2   = (const float*)d_in[4];
    const float* b2   = (const float*)d_in[5];
    const float* Wp   = (const float*)d_in[6];
    const float* bp   = (const float*)d_in[7];
    const float* Wz   = (const float*)d_in[8];
    const float* bz   = (const float*)d_in[9];
    const int*   ei   = (const int*)d_in[10];
    const int*   batch= (const int*)d_in[11];
    float* out = (float*)d_out;
    float* out_z = out;                   // [1024*8]
    float* out_s = out + N_GRAPHS * 8;    // [262144*2]

    // ws (ints): gcur[NBK*16] | binned[NBK*CAP] (=srcs after passC) |
    //            startg[N] | degg[N] | perm[N] | pooled[1025*32] | px16[N uint4]
    int* gcur     = (int*)d_ws;
    int* binned   = gcur + NBK * 16;
    int* startg   = binned + (size_t)NBK * CAP;
    int* degg     = startg + N_NODES;
    int* perm     = degg + N_NODES;
    float* pooled = (float*)(perm + N_NODES);
    uint4* px16   = (uint4*)(pooled + 1025 * 32);   // offset is 16B-aligned

    hipMemsetAsync(gcur, 0, NBK * 16 * sizeof(int), stream);
    fusedAB<<<ABLK, 256, 0, stream>>>(ei, x, pos, gcur, binned, px16, pooled);
    passC_sort<<<NBK, 512, 0, stream>>>(gcur, binned, startg, degg, perm);
    node_gather_fused<<<N_NODES / 16, 256, 0, stream>>>(
        px16, binned, startg, degg, perm, W1, b1, W2, b2, Wp, bp, batch, out_s, pooled);
    z_kernel<<<32, 256, 0, stream>>>(pooled, Wz, bz, out_z);
}